// Round 1
// baseline (121.285 us; speedup 1.0000x reference)
//
#include <hip/hip_runtime.h>

#define R    8
#define K    17           // 2*R+1
#define TILE 64
#define HALO (TILE + 2*R) // 80
#define W    512
#define H    512

__global__ __launch_bounds__(256)
void box_fused_kernel(const float* __restrict__ x, float* __restrict__ out) {
    const int plane = blockIdx.z;                 // n*C + c  (128 planes)
    const int gx0 = blockIdx.x * TILE;
    const int gy0 = blockIdx.y * TILE;
    const float* __restrict__ src = x   + (size_t)plane * (W * H);
    float* __restrict__       dst = out + (size_t)plane * (W * H);

    __shared__ float s_in[HALO][HALO + 1];  // 80x81 padded: 25,920 B
    __shared__ float s_h [HALO][TILE];      // 80x64:        20,480 B

    const int tid = threadIdx.x;
    const float inv_k = 1.0f / (float)K;

    // ---- load 80x80 halo region (zero padding outside image) ----
    for (int i = tid; i < HALO * HALO; i += 256) {
        int row = i / HALO;
        int col = i - row * HALO;
        int gy = gy0 - R + row;
        int gx = gx0 - R + col;
        float v = 0.0f;
        if ((unsigned)gy < (unsigned)H && (unsigned)gx < (unsigned)W)
            v = src[gy * W + gx];
        s_in[row][col] = v;
    }
    __syncthreads();

    // ---- horizontal pass: h[row][X] = inv_k * sum_{d=0..2R} s_in[row][X+d]
    // 80 rows x 4 segments of 16 outputs = 320 tasks, sliding window
    for (int task = tid; task < HALO * 4; task += 256) {
        int row = task >> 2;
        int seg = task & 3;
        int x0 = seg * 16;
        float sum = 0.0f;
        #pragma unroll
        for (int d = 0; d < K; ++d) sum += s_in[row][x0 + d];
        s_h[row][x0] = sum * inv_k;
        #pragma unroll
        for (int xx = 1; xx < 16; ++xx) {
            int X = x0 + xx;
            sum += s_in[row][X + 2 * R] - s_in[row][X - 1];
            s_h[row][X] = sum * inv_k;
        }
    }
    __syncthreads();

    // ---- vertical pass: out[y][x] = inv_k * sum_{j=y..y+2R} s_h[j][x]
    // thread = (column x, 16-row segment)
    const int xcol = tid & 63;
    const int seg  = tid >> 6;    // 0..3
    const int y0   = seg * 16;

    float sum = 0.0f;
    #pragma unroll
    for (int d = 0; d < K; ++d) sum += s_h[y0 + d][xcol];
    dst[(gy0 + y0) * W + gx0 + xcol] = sum * inv_k;
    #pragma unroll
    for (int yy = 1; yy < 16; ++yy) {
        int y = y0 + yy;
        sum += s_h[y + 2 * R][xcol] - s_h[y - 1][xcol];
        dst[(gy0 + y) * W + gx0 + xcol] = sum * inv_k;
    }
}

extern "C" void kernel_launch(void* const* d_in, const int* in_sizes, int n_in,
                              void* d_out, int out_size, void* d_ws, size_t ws_size,
                              hipStream_t stream) {
    const float* x = (const float*)d_in[0];
    float* out = (float*)d_out;
    // x: (8, 16, 512, 512) fp32; r = 8 (fixed by setup_inputs)
    dim3 grid(W / TILE, H / TILE, 8 * 16);   // (8, 8, 128)
    box_fused_kernel<<<grid, dim3(256), 0, stream>>>(x, out);
}

// Round 2
// 74.571 us; speedup vs baseline: 1.6265x; 1.6265x over previous
//
#include <hip/hip_runtime.h>

#define R    8
#define K    17           // 2*r+1
#define TILE 64
#define HALO (TILE + 2*R) // 80 columns incl. halo
#define W    512
#define H    512
#define LDSW 84           // padded row stride (mult of 4 for float4 align, !=mult32 banks)

__global__ __launch_bounds__(256)
void box_fused_v2(const float* __restrict__ x, float* __restrict__ out) {
    const int plane = blockIdx.z;                 // n*C + c  (128 planes)
    const int gx0 = blockIdx.x * TILE;
    const int gy0 = blockIdx.y * TILE;
    const float* __restrict__ src = x   + (size_t)plane * (W * H);
    float* __restrict__       dst = out + (size_t)plane * (W * H);

    // vertical-pass result: 64 output rows x 80 halo columns
    __shared__ __align__(16) float s_v[TILE][LDSW];   // 21,504 B -> 7 blocks/CU

    const int tid = threadIdx.x;
    const float inv_k = 1.0f / (float)K;

    // ---- Pass 1: vertical box sum, global -> registers -> LDS ----
    // 320 tasks = 80 halo-cols x 4 row-segments of 16 output rows
    for (int t = tid; t < HALO * 4; t += 256) {
        const int hc  = t % HALO;        // halo column 0..79 (lanes -> consecutive cols)
        const int seg = t / HALO;        // 0..3
        const int gx  = gx0 - R + hc;
        const bool colok = (unsigned)gx < (unsigned)W;
        const int gy_start = gy0 + seg * 16 - R;   // first input row needed

        float rr[32];
        #pragma unroll
        for (int j = 0; j < 32; ++j) {
            const int gy = gy_start + j;
            float v = 0.0f;
            if (colok && (unsigned)gy < (unsigned)H)
                v = src[gy * W + gx];
            rr[j] = v;
        }
        float s = 0.0f;
        #pragma unroll
        for (int j = 0; j < K; ++j) s += rr[j];
        s_v[seg * 16 + 0][hc] = s * inv_k;
        #pragma unroll
        for (int i = 1; i < 16; ++i) {
            s += rr[i + 2 * R] - rr[i - 1];
            s_v[seg * 16 + i][hc] = s * inv_k;
        }
    }
    __syncthreads();

    // ---- Pass 2: horizontal box sum, LDS (float4) -> global (float4) ----
    // thread = (row-slot rs 0..15, x-quad xq 0..15); each does 4 rows
    const int xq = tid & 15;          // 16 quads -> 64 output cols
    const int rs = tid >> 4;          // 0..15
    const int x4 = xq * 4;            // output col offset (== left halo col of window)

    #pragma unroll
    for (int j = 0; j < 4; ++j) {
        const int y = rs * 4 + j;     // 0..63
        const float4 f0 = *reinterpret_cast<const float4*>(&s_v[y][x4]);
        const float4 f1 = *reinterpret_cast<const float4*>(&s_v[y][x4 + 4]);
        const float4 f2 = *reinterpret_cast<const float4*>(&s_v[y][x4 + 8]);
        const float4 f3 = *reinterpret_cast<const float4*>(&s_v[y][x4 + 12]);
        const float4 f4 = *reinterpret_cast<const float4*>(&s_v[y][x4 + 16]);

        float o0 = f0.x + f0.y + f0.z + f0.w
                 + f1.x + f1.y + f1.z + f1.w
                 + f2.x + f2.y + f2.z + f2.w
                 + f3.x + f3.y + f3.z + f3.w
                 + f4.x;                              // 17 taps
        const float o1 = o0 - f0.x + f4.y;
        const float o2 = o1 - f0.y + f4.z;
        const float o3 = o2 - f0.z + f4.w;

        float4 o;
        o.x = o0 * inv_k; o.y = o1 * inv_k; o.z = o2 * inv_k; o.w = o3 * inv_k;
        *reinterpret_cast<float4*>(&dst[(gy0 + y) * W + gx0 + x4]) = o;
    }
}

extern "C" void kernel_launch(void* const* d_in, const int* in_sizes, int n_in,
                              void* d_out, int out_size, void* d_ws, size_t ws_size,
                              hipStream_t stream) {
    const float* x = (const float*)d_in[0];
    float* out = (float*)d_out;
    // x: (8, 16, 512, 512) fp32; r = 8 fixed
    dim3 grid(W / TILE, H / TILE, 8 * 16);   // (8, 8, 128)
    box_fused_v2<<<grid, dim3(256), 0, stream>>>(x, out);
}

// Round 3
// 67.374 us; speedup vs baseline: 1.8002x; 1.1068x over previous
//
#include <hip/hip_runtime.h>

#define R    8
#define K    17           // 2*r+1
#define TILE 64
#define HALO (TILE + 2*R) // 80 columns incl. halo
#define W    512
#define H    512
#define LDSW 84           // padded row stride (84%8==4 breaks bank alignment, mult-of-4 keeps float4 align)

// Block = 320 threads (5 waves): pass 1 has exactly 320 tasks -> one per
// thread, no wave does double work before the barrier. 6 blocks/CU
// (wave-slot limited: 6*5=30 of 32 waves), LDS 6*21.5KB = 129KB of 160KB.
__global__ __launch_bounds__(320)
void box_fused_v3(const float* __restrict__ x, float* __restrict__ out) {
    const int plane = blockIdx.z;                 // n*C + c  (128 planes)
    const int gx0 = blockIdx.x * TILE;
    const int gy0 = blockIdx.y * TILE;
    const float* __restrict__ src = x   + (size_t)plane * (W * H);
    float* __restrict__       dst = out + (size_t)plane * (W * H);

    // vertical-pass result: 64 output rows x 80 halo columns
    __shared__ __align__(16) float s_v[TILE][LDSW];   // 21,504 B

    const int tid = threadIdx.x;
    const float inv_k = 1.0f / (float)K;

    // ---- Pass 1: vertical box sum, global -> registers -> LDS ----
    // exactly one task per thread: 320 = 80 halo-cols x 4 row-segments
    {
        const int hc  = tid % HALO;      // halo column 0..79
        const int seg = tid / HALO;      // 0..3
        const int gx  = gx0 - R + hc;
        const bool colok = (unsigned)gx < (unsigned)W;
        const int gy_start = gy0 + seg * 16 - R;   // first input row needed

        float rr[32];
        #pragma unroll
        for (int j = 0; j < 32; ++j) {
            const int gy = gy_start + j;
            float v = 0.0f;
            if (colok && (unsigned)gy < (unsigned)H)
                v = src[gy * W + gx];
            rr[j] = v;
        }
        float s = 0.0f;
        #pragma unroll
        for (int j = 0; j < K; ++j) s += rr[j];
        s_v[seg * 16 + 0][hc] = s * inv_k;
        #pragma unroll
        for (int i = 1; i < 16; ++i) {
            s += rr[i + 2 * R] - rr[i - 1];
            s_v[seg * 16 + i][hc] = s * inv_k;
        }
    }
    __syncthreads();

    // ---- Pass 2: horizontal box sum, LDS (float4) -> global (float4) ----
    // 1024 quad-tasks (64 rows x 16 x-quads) over 320 threads
    for (int q = tid; q < TILE * 16; q += 320) {
        const int y  = q >> 4;          // 0..63
        const int x4 = (q & 15) * 4;    // output col offset

        const float4 f0 = *reinterpret_cast<const float4*>(&s_v[y][x4]);
        const float4 f1 = *reinterpret_cast<const float4*>(&s_v[y][x4 + 4]);
        const float4 f2 = *reinterpret_cast<const float4*>(&s_v[y][x4 + 8]);
        const float4 f3 = *reinterpret_cast<const float4*>(&s_v[y][x4 + 12]);
        const float4 f4 = *reinterpret_cast<const float4*>(&s_v[y][x4 + 16]);

        float o0 = f0.x + f0.y + f0.z + f0.w
                 + f1.x + f1.y + f1.z + f1.w
                 + f2.x + f2.y + f2.z + f2.w
                 + f3.x + f3.y + f3.z + f3.w
                 + f4.x;                              // 17 taps
        const float o1 = o0 - f0.x + f4.y;
        const float o2 = o1 - f0.y + f4.z;
        const float o3 = o2 - f0.z + f4.w;

        float4 o;
        o.x = o0 * inv_k; o.y = o1 * inv_k; o.z = o2 * inv_k; o.w = o3 * inv_k;
        *reinterpret_cast<float4*>(&dst[(gy0 + y) * W + gx0 + x4]) = o;
    }
}

extern "C" void kernel_launch(void* const* d_in, const int* in_sizes, int n_in,
                              void* d_out, int out_size, void* d_ws, size_t ws_size,
                              hipStream_t stream) {
    const float* x = (const float*)d_in[0];
    float* out = (float*)d_out;
    // x: (8, 16, 512, 512) fp32; r = 8 fixed
    dim3 grid(W / TILE, H / TILE, 8 * 16);   // (8, 8, 128)
    box_fused_v3<<<grid, dim3(320), 0, stream>>>(x, out);
}

// Round 4
// 61.189 us; speedup vs baseline: 1.9822x; 1.1011x over previous
//
#include <hip/hip_runtime.h>

#define R      8
#define K      17               // 2*r+1
#define W      512
#define H      512
#define ROWS   16               // output rows per block
#define INROWS (ROWS + 2*R)     // 32 input rows
#define LDSW   532              // 8 halo + 512 + 8 halo + 4 pad (16B-aligned rows)

// Strip-tile fused box filter: vertical pass (regs) -> LDS -> horizontal pass.
// 512 threads (8 waves), LDS 34,048 B -> 4 blocks/CU, 32/32 wave slots.
__global__ __launch_bounds__(512, 8)
void box_strip(const float* __restrict__ x, float* __restrict__ out) {
    const int plane = blockIdx.y;              // n*C + c (128 planes)
    const int gy0   = blockIdx.x * ROWS;       // strip start row
    const float* __restrict__ src = x   + (size_t)plane * (W * H);
    float* __restrict__       dst = out + (size_t)plane * (W * H);

    __shared__ __align__(16) float s_v[ROWS][LDSW];

    const int tid = threadIdx.x;
    const float inv_k = 1.0f / (float)K;

    // ---- zero the horizontal halo columns (image cols -8..-1 and 512..519) ----
    if (tid < 256) {
        const int row = tid >> 4;
        const int c   = tid & 15;
        const int col = (c < 8) ? c : (8 + 512 + (c - 8));   // 0..7 or 520..527
        s_v[row][col] = 0.0f;
    }

    // ---- Pass 1: vertical box sum. One column per thread, 32 rows ----
    {
        const int col      = tid;              // 0..511, wave -> contiguous 256B
        const int gy_start = gy0 - R;

        float rr[INROWS];
        #pragma unroll
        for (int j = 0; j < INROWS; ++j) {
            const int gy = gy_start + j;
            float v = 0.0f;
            if ((unsigned)gy < (unsigned)H)
                v = src[gy * W + col];
            rr[j] = v;
        }
        // Pin every load's result live here: forces all 32 loads issued
        // back-to-back (full ILP, one vmcnt drain) instead of the
        // compiler's register-minimizing serialized schedule (R3: VGPR=20).
        #pragma unroll
        for (int j = 0; j < INROWS; ++j) asm volatile("" : "+v"(rr[j]));

        float s = 0.0f;
        #pragma unroll
        for (int j = 0; j < K; ++j) s += rr[j];
        s_v[0][8 + col] = s * inv_k;
        #pragma unroll
        for (int i = 1; i < ROWS; ++i) {
            s += rr[i + 2 * R] - rr[i - 1];
            s_v[i][8 + col] = s * inv_k;
        }
    }
    __syncthreads();

    // ---- Pass 2: horizontal box sum, LDS float4 -> global float4 ----
    // 2048 quad-tasks (16 rows x 128 quads) over 512 threads = 4 iters
    #pragma unroll
    for (int it = 0; it < 4; ++it) {
        const int q  = tid + it * 512;
        const int y  = q >> 7;                 // 0..15
        const int x4 = (q & 127) * 4;          // 0..508

        const float4 f0 = *reinterpret_cast<const float4*>(&s_v[y][x4]);
        const float4 f1 = *reinterpret_cast<const float4*>(&s_v[y][x4 + 4]);
        const float4 f2 = *reinterpret_cast<const float4*>(&s_v[y][x4 + 8]);
        const float4 f3 = *reinterpret_cast<const float4*>(&s_v[y][x4 + 12]);
        const float4 f4 = *reinterpret_cast<const float4*>(&s_v[y][x4 + 16]);

        float o0 = f0.x + f0.y + f0.z + f0.w
                 + f1.x + f1.y + f1.z + f1.w
                 + f2.x + f2.y + f2.z + f2.w
                 + f3.x + f3.y + f3.z + f3.w
                 + f4.x;                       // 17 taps, window [x4-8 .. x4+8]
        const float o1 = o0 - f0.x + f4.y;
        const float o2 = o1 - f0.y + f4.z;
        const float o3 = o2 - f0.z + f4.w;

        float4 o;
        o.x = o0 * inv_k; o.y = o1 * inv_k; o.z = o2 * inv_k; o.w = o3 * inv_k;
        *reinterpret_cast<float4*>(&dst[(gy0 + y) * W + x4]) = o;
    }
}

extern "C" void kernel_launch(void* const* d_in, const int* in_sizes, int n_in,
                              void* d_out, int out_size, void* d_ws, size_t ws_size,
                              hipStream_t stream) {
    const float* x = (const float*)d_in[0];
    float* out = (float*)d_out;
    // x: (8, 16, 512, 512) fp32; r = 8 fixed
    dim3 grid(H / ROWS, 8 * 16);   // (32 strips, 128 planes)
    box_strip<<<grid, dim3(512), 0, stream>>>(x, out);
}